// Round 1
// baseline (526.376 us; speedup 1.0000x reference)
//
#include <hip/hip_runtime.h>
#include <hip/hip_bf16.h>

#define DIM 768
#define HEADS 12
#define HD 64
#define HIDDEN 3072
#define SEQ 1024
#define NB 8
#define M_TOK (NB * SEQ)   // 8192 tokens
#define C3 (3 * DIM)       // 2304

typedef __attribute__((ext_vector_type(8))) short short8;   // 8 x bf16 (4 VGPRs)
typedef __attribute__((ext_vector_type(4))) float floatx4;  // MFMA accum

__device__ __forceinline__ void gload_lds16(const void* g, void* l) {
  __builtin_amdgcn_global_load_lds((const __attribute__((address_space(1))) void*)g,
                                   (__attribute__((address_space(3))) void*)l, 16, 0, 0);
}

// ---------------------------------------------------------------------------
// Weight transpose + f32->bf16 cast: w[K][N] -> wt[N][K]
// ---------------------------------------------------------------------------
__global__ __launch_bounds__(256) void transpose_cast(
    const float* __restrict__ w, __hip_bfloat16* __restrict__ wt, int K, int N) {
  __shared__ float tile[32][33];
  const int tx = threadIdx.x & 31, ty = threadIdx.x >> 5;
  const int n0 = blockIdx.x * 32, k0 = blockIdx.y * 32;
#pragma unroll
  for (int i = 0; i < 32; i += 8)
    tile[ty + i][tx] = w[(size_t)(k0 + ty + i) * N + n0 + tx];
  __syncthreads();
#pragma unroll
  for (int i = 0; i < 32; i += 8)
    wt[(size_t)(n0 + ty + i) * K + k0 + tx] = __float2bfloat16(tile[tx][ty + i]);
}

// ---------------------------------------------------------------------------
// LayerNorm (f32 in) -> bf16 out.  One block per row of 768.
// ---------------------------------------------------------------------------
__global__ __launch_bounds__(256) void ln_kernel(
    const float* __restrict__ x, const float* __restrict__ gw,
    const float* __restrict__ bw, __hip_bfloat16* __restrict__ outp) {
  const int row = blockIdx.x;
  const int t = threadIdx.x;
  const float* xr = x + (size_t)row * DIM;
  float v0 = xr[t], v1 = xr[t + 256], v2 = xr[t + 512];
  float s = v0 + v1 + v2;
  float sq = v0 * v0 + v1 * v1 + v2 * v2;
#pragma unroll
  for (int m = 1; m < 64; m <<= 1) {
    s += __shfl_xor(s, m);
    sq += __shfl_xor(sq, m);
  }
  __shared__ float ss[4], ssq[4];
  const int wave = t >> 6, lane = t & 63;
  if (lane == 0) { ss[wave] = s; ssq[wave] = sq; }
  __syncthreads();
  s = ss[0] + ss[1] + ss[2] + ss[3];
  sq = ssq[0] + ssq[1] + ssq[2] + ssq[3];
  const float mean = s * (1.f / 768.f);
  const float var = sq * (1.f / 768.f) - mean * mean;
  const float rstd = rsqrtf(var + 1e-5f);
  __hip_bfloat16* orow = outp + (size_t)row * DIM;
  orow[t]       = __float2bfloat16((v0 - mean) * rstd * gw[t]       + bw[t]);
  orow[t + 256] = __float2bfloat16((v1 - mean) * rstd * gw[t + 256] + bw[t + 256]);
  orow[t + 512] = __float2bfloat16((v2 - mean) * rstd * gw[t + 512] + bw[t + 512]);
}

// ---------------------------------------------------------------------------
// GEMM: C[M][N] = A[M][K] (bf16) @ BT[N][K]^T (bf16)  [+bias][gelu][+resid]
// 128x128 tile, BK=64, 4 waves (2x2), 4x4 16x16x32 fragments per wave.
// ---------------------------------------------------------------------------
template <int BIAS, int GELU, int RES, int OBF16>
__global__ __launch_bounds__(256) void gemm_bt(
    const __hip_bfloat16* __restrict__ A, const __hip_bfloat16* __restrict__ BT,
    const float* __restrict__ bias, const float* __restrict__ resid,
    void* __restrict__ Cout, int M, int N, int K) {
  __shared__ __align__(16) __hip_bfloat16 As[128 * 64];
  __shared__ __align__(16) __hip_bfloat16 Bs[128 * 64];
  const int tid = threadIdx.x;
  const int wave = tid >> 6, lane = tid & 63;
  const int g = lane >> 4, fr = lane & 15;
  const int m0 = blockIdx.y * 128, n0 = blockIdx.x * 128;
  const int wm = (wave >> 1) * 64, wn = (wave & 1) * 64;

  floatx4 acc[4][4];
  const floatx4 zero = {0.f, 0.f, 0.f, 0.f};
#pragma unroll
  for (int m = 0; m < 4; ++m)
#pragma unroll
    for (int n = 0; n < 4; ++n) acc[m][n] = zero;

  for (int kt = 0; kt < K; kt += 64) {
#pragma unroll
    for (int i = 0; i < 4; ++i) {
      const int li = i * 256 + tid;
      const int row = li >> 3, k8 = (li & 7) << 3;
      gload_lds16(A + (size_t)(m0 + row) * K + kt + k8, As + li * 8);
      gload_lds16(BT + (size_t)(n0 + row) * K + kt + k8, Bs + li * 8);
    }
    __syncthreads();
#pragma unroll
    for (int kk = 0; kk < 64; kk += 32) {
      short8 af[4], bfr[4];
#pragma unroll
      for (int m = 0; m < 4; ++m)
        af[m] = *(const short8*)(As + (wm + m * 16 + fr) * 64 + kk + g * 8);
#pragma unroll
      for (int n = 0; n < 4; ++n)
        bfr[n] = *(const short8*)(Bs + (wn + n * 16 + fr) * 64 + kk + g * 8);
#pragma unroll
      for (int m = 0; m < 4; ++m)
#pragma unroll
        for (int n = 0; n < 4; ++n)
          acc[m][n] = __builtin_amdgcn_mfma_f32_16x16x32_bf16(af[m], bfr[n], acc[m][n], 0, 0, 0);
    }
    __syncthreads();
  }

#pragma unroll
  for (int m = 0; m < 4; ++m) {
    const int row = m0 + wm + m * 16 + g * 4;
#pragma unroll
    for (int n = 0; n < 4; ++n) {
      const int col = n0 + wn + n * 16 + fr;
      const float bv = BIAS ? bias[col] : 0.f;
#pragma unroll
      for (int r = 0; r < 4; ++r) {
        float c = acc[m][n][r] + bv;
        if (GELU) c = 0.5f * c * (1.f + erff(c * 0.70710678118f));
        const size_t off = (size_t)(row + r) * N + col;
        if (RES) c += resid[off];
        if (OBF16) ((__hip_bfloat16*)Cout)[off] = __float2bfloat16(c);
        else       ((float*)Cout)[off] = c;
      }
    }
  }
}

// ---------------------------------------------------------------------------
// Flash attention: grid (S/64, B*H). 4 waves/block, 16 q-rows per wave.
// Q in regs; K fragments direct from global; online softmax (16-lane groups);
// P transposed through per-wave LDS; V scalar-gathered from global.
// ---------------------------------------------------------------------------
__global__ __launch_bounds__(256) void attn_kernel(
    const __hip_bfloat16* __restrict__ qkv, __hip_bfloat16* __restrict__ outp) {
  const int wave = threadIdx.x >> 6, lane = threadIdx.x & 63;
  const int g = lane >> 4, fr = lane & 15;
  const int qt = blockIdx.x;
  const int bh = blockIdx.y;
  const int b = bh / HEADS, h = bh % HEADS;

  const size_t base = (size_t)b * SEQ * C3;
  const int q0 = qt * 64 + wave * 16;

  const __hip_bfloat16* qp = qkv + base + (size_t)(q0 + fr) * C3 + h * HD;
  const short8 qf0 = *(const short8*)(qp + g * 8);
  const short8 qf1 = *(const short8*)(qp + 32 + g * 8);

  const __hip_bfloat16* kbase = qkv + base + DIM + h * HD;
  const unsigned short* vbase = (const unsigned short*)(qkv + base + 2 * DIM + h * HD);

  __shared__ __align__(16) __hip_bfloat16 P[4][16 * 32];

  float m_r[4], l_r[4];
  floatx4 acc_o[4];
  const floatx4 zero = {0.f, 0.f, 0.f, 0.f};
#pragma unroll
  for (int r = 0; r < 4; ++r) { m_r[r] = -1e30f; l_r[r] = 0.f; }
#pragma unroll
  for (int n = 0; n < 4; ++n) acc_o[n] = zero;

  for (int kt = 0; kt < SEQ; kt += 32) {
    floatx4 sa0 = zero, sa1 = zero;
    {
      const __hip_bfloat16* kp0 = kbase + (size_t)(kt + fr) * C3;
      const __hip_bfloat16* kp1 = kbase + (size_t)(kt + 16 + fr) * C3;
      const short8 k00 = *(const short8*)(kp0 + g * 8);
      const short8 k01 = *(const short8*)(kp0 + 32 + g * 8);
      const short8 k10 = *(const short8*)(kp1 + g * 8);
      const short8 k11 = *(const short8*)(kp1 + 32 + g * 8);
      sa0 = __builtin_amdgcn_mfma_f32_16x16x32_bf16(qf0, k00, sa0, 0, 0, 0);
      sa0 = __builtin_amdgcn_mfma_f32_16x16x32_bf16(qf1, k01, sa0, 0, 0, 0);
      sa1 = __builtin_amdgcn_mfma_f32_16x16x32_bf16(qf0, k10, sa1, 0, 0, 0);
      sa1 = __builtin_amdgcn_mfma_f32_16x16x32_bf16(qf1, k11, sa1, 0, 0, 0);
    }
#pragma unroll
    for (int r = 0; r < 4; ++r) {
      const float s0 = sa0[r] * 0.125f, s1 = sa1[r] * 0.125f;
      float mx = fmaxf(s0, s1);
      mx = fmaxf(mx, __shfl_xor(mx, 1));
      mx = fmaxf(mx, __shfl_xor(mx, 2));
      mx = fmaxf(mx, __shfl_xor(mx, 4));
      mx = fmaxf(mx, __shfl_xor(mx, 8));
      const float mn = fmaxf(m_r[r], mx);
      const float alpha = __expf(m_r[r] - mn);
      const float p0 = __expf(s0 - mn);
      const float p1 = __expf(s1 - mn);
      float rs = p0 + p1;
      rs += __shfl_xor(rs, 1);
      rs += __shfl_xor(rs, 2);
      rs += __shfl_xor(rs, 4);
      rs += __shfl_xor(rs, 8);
      l_r[r] = l_r[r] * alpha + rs;
      m_r[r] = mn;
#pragma unroll
      for (int n = 0; n < 4; ++n) acc_o[n][r] *= alpha;
      P[wave][(g * 4 + r) * 32 + fr]      = __float2bfloat16(p0);
      P[wave][(g * 4 + r) * 32 + 16 + fr] = __float2bfloat16(p1);
    }
    const short8 pf = *(const short8*)(&P[wave][fr * 32 + g * 8]);
#pragma unroll
    for (int n = 0; n < 4; ++n) {
      short8 vf;
#pragma unroll
      for (int j = 0; j < 8; ++j)
        ((unsigned short*)&vf)[j] = vbase[(size_t)(kt + g * 8 + j) * C3 + n * 16 + fr];
      acc_o[n] = __builtin_amdgcn_mfma_f32_16x16x32_bf16(pf, vf, acc_o[n], 0, 0, 0);
    }
  }

  __hip_bfloat16* op = outp + (size_t)(b * SEQ + q0) * DIM + h * HD;
#pragma unroll
  for (int n = 0; n < 4; ++n)
#pragma unroll
    for (int r = 0; r < 4; ++r)
      op[(size_t)(g * 4 + r) * DIM + n * 16 + fr] =
          __float2bfloat16(acc_o[n][r] / l_r[r]);
}

// ---------------------------------------------------------------------------
extern "C" void kernel_launch(void* const* d_in, const int* in_sizes, int n_in,
                              void* d_out, int out_size, void* d_ws, size_t ws_size,
                              hipStream_t stream) {
  (void)in_sizes; (void)n_in; (void)out_size; (void)ws_size;
  const float* x      = (const float*)d_in[0];
  const float* ln1_g  = (const float*)d_in[1];
  const float* ln1_b  = (const float*)d_in[2];
  const float* w_qkv  = (const float*)d_in[3];
  const float* w_proj = (const float*)d_in[4];
  const float* b_proj = (const float*)d_in[5];
  const float* ln2_g  = (const float*)d_in[6];
  const float* ln2_b  = (const float*)d_in[7];
  const float* w_fc1  = (const float*)d_in[8];
  const float* b_fc1  = (const float*)d_in[9];
  const float* w_fc2  = (const float*)d_in[10];
  const float* b_fc2  = (const float*)d_in[11];
  float* outp = (float*)d_out;

  char* ws = (char*)d_ws;
  size_t off = 0;
  auto alloc = [&](size_t bytes) -> void* {
    void* p = ws + off;
    off += (bytes + 255) & ~(size_t)255;
    return p;
  };
  __hip_bfloat16* h1     = (__hip_bfloat16*)alloc((size_t)M_TOK * DIM * 2);
  __hip_bfloat16* qkv    = (__hip_bfloat16*)alloc((size_t)M_TOK * C3 * 2);
  __hip_bfloat16* att    = (__hip_bfloat16*)alloc((size_t)M_TOK * DIM * 2);
  __hip_bfloat16* h2     = (__hip_bfloat16*)alloc((size_t)M_TOK * DIM * 2);
  __hip_bfloat16* act    = (__hip_bfloat16*)alloc((size_t)M_TOK * HIDDEN * 2);
  __hip_bfloat16* wqkvT  = (__hip_bfloat16*)alloc((size_t)C3 * DIM * 2);
  __hip_bfloat16* wprojT = (__hip_bfloat16*)alloc((size_t)DIM * DIM * 2);
  __hip_bfloat16* wfc1T  = (__hip_bfloat16*)alloc((size_t)HIDDEN * DIM * 2);
  __hip_bfloat16* wfc2T  = (__hip_bfloat16*)alloc((size_t)DIM * HIDDEN * 2);
  float* x_mid = outp;  // mid-residual lives in d_out (fully rewritten each call)

  transpose_cast<<<dim3(C3 / 32, DIM / 32), 256, 0, stream>>>(w_qkv, wqkvT, DIM, C3);
  transpose_cast<<<dim3(DIM / 32, DIM / 32), 256, 0, stream>>>(w_proj, wprojT, DIM, DIM);
  transpose_cast<<<dim3(HIDDEN / 32, DIM / 32), 256, 0, stream>>>(w_fc1, wfc1T, DIM, HIDDEN);
  transpose_cast<<<dim3(DIM / 32, HIDDEN / 32), 256, 0, stream>>>(w_fc2, wfc2T, HIDDEN, DIM);

  ln_kernel<<<M_TOK, 256, 0, stream>>>(x, ln1_g, ln1_b, h1);
  gemm_bt<0, 0, 0, 1><<<dim3(C3 / 128, M_TOK / 128), 256, 0, stream>>>(
      h1, wqkvT, nullptr, nullptr, qkv, M_TOK, C3, DIM);
  attn_kernel<<<dim3(SEQ / 64, NB * HEADS), 256, 0, stream>>>(qkv, att);
  gemm_bt<1, 0, 1, 0><<<dim3(DIM / 128, M_TOK / 128), 256, 0, stream>>>(
      att, wprojT, b_proj, x, x_mid, M_TOK, DIM, DIM);
  ln_kernel<<<M_TOK, 256, 0, stream>>>(x_mid, ln2_g, ln2_b, h2);
  gemm_bt<1, 1, 0, 1><<<dim3(HIDDEN / 128, M_TOK / 128), 256, 0, stream>>>(
      h2, wfc1T, b_fc1, nullptr, act, M_TOK, HIDDEN, DIM);
  gemm_bt<1, 0, 1, 0><<<dim3(DIM / 128, M_TOK / 128), 256, 0, stream>>>(
      act, wfc2T, b_fc2, x_mid, outp, M_TOK, DIM, HIDDEN);
}